// Round 13
// baseline (143.619 us; speedup 1.0000x reference)
//
#include <hip/hip_runtime.h>

#define NN 10000
#define NE 40000

typedef __attribute__((ext_vector_type(8))) short bf16x8;
typedef __attribute__((ext_vector_type(4))) float f32x4;
typedef __attribute__((ext_vector_type(8))) unsigned short u16x8;

__device__ inline unsigned short bf16rne(float f) {
  union { float f; unsigned u; } v; v.f = f;
  return (unsigned short)((v.u + 0x7FFFu + ((v.u >> 16) & 1u)) >> 16);
}

// ---- CSR setup kernels -----------------------------------------------------
__global__ void k_zero(int* __restrict__ p, int n) {
  int i = blockIdx.x * 256 + threadIdx.x;
  if (i < n) p[i] = 0;
}
__global__ void k_hist(const int* __restrict__ dst, int* __restrict__ cnt) {
  int e = blockIdx.x * 256 + threadIdx.x;
  if (e < NE) atomicAdd(&cnt[dst[e]], 1);
}
// single-block inclusive scan over cnt[NN] -> off[1..NN], off[0]=0
__global__ void k_scan(const int* __restrict__ cnt, int* __restrict__ off) {
  __shared__ int s[1024];
  __shared__ int carry;
  const int tid = threadIdx.x;
  if (tid == 0) carry = 0;
  __syncthreads();
  for (int base = 0; base < NN; base += 1024) {
    int v = (base + tid < NN) ? cnt[base + tid] : 0;
    s[tid] = v;
    __syncthreads();
    for (int d = 1; d < 1024; d <<= 1) {
      int t = (tid >= d) ? s[tid - d] : 0;
      __syncthreads();
      s[tid] += t;
      __syncthreads();
    }
    if (base + tid < NN) off[base + tid + 1] = carry + s[tid];
    __syncthreads();
    if (tid == 0) carry += s[1023];
    __syncthreads();
  }
  if (tid == 0) off[0] = 0;
}
__global__ void k_seed(const int* __restrict__ off, int* __restrict__ cursor) {
  int i = blockIdx.x * 256 + threadIdx.x;
  if (i < NN) cursor[i] = off[i];
}
__global__ void k_scatter(const int* __restrict__ dst, int* __restrict__ cursor,
                          int* __restrict__ order) {
  int e = blockIdx.x * 256 + threadIdx.x;
  if (e < NE) { int p = atomicAdd(&cursor[dst[e]], 1); order[p] = e; }
}

// ---- weight reorder kernels ------------------------------------------------
__global__ void k_reorder(const float* __restrict__ ew2, unsigned short* __restrict__ out) {
  const int l  = threadIdx.x & 63;
  const int kk = threadIdx.x >> 6;
  const int ct = blockIdx.x;
  const int col = ct * 16 + (l & 15);
  const int g = l >> 4;
  u16x8 v;
#pragma unroll
  for (int j = 0; j < 8; ++j) v[j] = bf16rne(ew2[(kk * 32 + g * 8 + j) * 2048 + col]);
  *reinterpret_cast<u16x8*>(out + ((size_t)(ct * 2048 + kk * 512 + l * 8))) = v;
}
__global__ void k_reorder_e(const float* __restrict__ ew1, unsigned short* __restrict__ out) {
  const int l  = threadIdx.x & 63;
  const int ct = threadIdx.x >> 6;
  const int g = l >> 4;
  u16x8 v;
#pragma unroll
  for (int j = 0; j < 8; ++j) {
    int k = g * 8 + j;
    v[j] = (k < 16) ? bf16rne(ew1[k * 128 + ct * 16 + (l & 15)]) : (unsigned short)0;
  }
  *reinterpret_cast<u16x8*>(out + ((size_t)(ct * 64 + l) * 8)) = v;
}

// out[n,KO] = (relu?)(xin[n,KI]) @ root[KI,KO] + bias[KO]
template <int KI, int KO, bool RELU_IN>
__global__ void k_root(const float* __restrict__ xin, const float* __restrict__ root,
                       const float* __restrict__ bias, float* __restrict__ out) {
  int idx = blockIdx.x * 256 + threadIdx.x;
  if (idx >= NN * KO) return;
  int n = idx / KO, o = idx % KO;
  float acc = bias[o];
#pragma unroll
  for (int k = 0; k < KI; ++k) {
    float v = xin[n * KI + k];
    if (RELU_IN) v = fmaxf(v, 0.f);
    acc += v * root[k * KO + o];
  }
  out[idx] = acc;
}

// ---- fused per-edge kernel (R3 structure; MODE 0=atomic, 1=store) ----------
template <int CI, int CO, bool RELU_IN, int MODE>
__global__ __launch_bounds__(256, 2) void k_edge(
    const int* __restrict__ src, const int* __restrict__ dst,
    const float* __restrict__ eattr,
    const unsigned short* __restrict__ ew1f, const float* __restrict__ eb1,
    const unsigned short* __restrict__ bfrag, const float* __restrict__ eb2,
    const float* __restrict__ xin, float* aggr, float* m0, float* m1) {
  constexpr int TE = 64;
  const int tid = threadIdx.x;
  const int e0 = blockIdx.x * TE;

  __shared__ int s_src[TE];
  __shared__ int s_dst[TE];
  __shared__ float s_x[CI][68];
  __shared__ unsigned short s_hfrag[16 * 64 * 8];  // 16 KB

  if (tid < TE) { s_src[tid] = src[e0 + tid]; s_dst[tid] = dst[e0 + tid]; }
  __syncthreads();

  for (int idx = tid; idx < TE * CI; idx += 256) {
    int e = idx / CI, c = idx % CI;
    float v = xin[(size_t)s_src[e] * CI + c];
    if (RELU_IN) v = fmaxf(v, 0.f);
    s_x[c][e] = v;
  }

  const int l = tid & 63, w = tid >> 6, g = l >> 4, c16 = l & 15;

  // H phase via MFMA: wave w -> edge tile m=w, all 128 channels
  {
    const int m = w;
    bf16x8 ea;
#pragma unroll
    for (int j = 0; j < 8; ++j) ea[j] = 0;
    if (g < 2) {
      const float* p = eattr + (size_t)(e0 + 16 * m + c16) * 16 + g * 8;
      f32x4 v0 = *reinterpret_cast<const f32x4*>(p);
      f32x4 v1 = *reinterpret_cast<const f32x4*>(p + 4);
#pragma unroll
      for (int j = 0; j < 4; ++j) { ea[j] = bf16rne(v0[j]); ea[4 + j] = bf16rne(v1[j]); }
    }
#pragma unroll
    for (int ct = 0; ct < 8; ++ct) {
      bf16x8 bw = *reinterpret_cast<const bf16x8*>(ew1f + (size_t)(ct * 64 + l) * 8);
      const float bb = eb1[ct * 16 + c16];
      f32x4 acc = {bb, bb, bb, bb};
      acc = __builtin_amdgcn_mfma_f32_16x16x32_bf16(ea, bw, acc, 0, 0, 0);
#pragma unroll
      for (int r = 0; r < 4; ++r) {
        const int c = ct * 16 + c16;
        s_hfrag[(((m * 4) + (c >> 5)) * 64 + ((c >> 3) & 3) * 16 + g * 4 + r) * 8 + (c & 7)] =
            bf16rne(fmaxf(acc[r], 0.f));
      }
    }
  }
  __syncthreads();

  bf16x8 afrag[4][4];
#pragma unroll
  for (int m = 0; m < 4; ++m)
#pragma unroll
    for (int kk = 0; kk < 4; ++kk)
      afrag[m][kk] = *reinterpret_cast<const bf16x8*>(&s_hfrag[((m * 4 + kk) * 64 + l) * 8]);

  float msg[4][4];
#pragma unroll
  for (int m = 0; m < 4; ++m)
#pragma unroll
    for (int r = 0; r < 4; ++r) msg[m][r] = 0.f;

  const int ocol = (CI == 32) ? (w * 16 + c16) : ((w & 1) * 16 + c16);
  const bf16x8* Bb = reinterpret_cast<const bf16x8*>(bfrag);

  bf16x8 bA[4], bB[4];

#define PREF(T, BUF)                                                             \
  {                                                                              \
    const int i_ = (CI == 32) ? (T) : ((w >> 1) + 2 * (T));                      \
    const int ct_ = (CI == 32) ? ((T) * 4 + w) : (i_ * 2 + (w & 1));             \
    const bf16x8* bp_ = Bb + (size_t)ct_ * 256 + l;                              \
    _Pragma("unroll") for (int kk = 0; kk < 4; ++kk) BUF[kk] = bp_[kk * 64];     \
  }

#define COMP(T, BUF)                                                             \
  {                                                                              \
    const int i_ = (CI == 32) ? (T) : ((w >> 1) + 2 * (T));                      \
    const float bb = eb2[i_ * CO + ocol];                                        \
    _Pragma("unroll") for (int m = 0; m < 4; ++m) {                              \
      f32x4 wacc = {0.f, 0.f, 0.f, 0.f};                                         \
      _Pragma("unroll") for (int kk = 0; kk < 4; ++kk)                           \
          wacc = __builtin_amdgcn_mfma_f32_16x16x32_bf16(afrag[m][kk], BUF[kk],  \
                                                         wacc, 0, 0, 0);         \
      const f32x4 xs = *reinterpret_cast<const f32x4*>(&s_x[i_][m * 16 + g * 4]);\
      _Pragma("unroll") for (int r = 0; r < 4; ++r)                              \
          msg[m][r] += fmaxf(wacc[r] + bb, 0.f) * xs[r];                         \
    }                                                                            \
  }

  PREF(0, bA)
#pragma unroll 1
  for (int t = 0; t < 30; t += 2) {
    PREF(t + 1, bB)
    COMP(t, bA)
    PREF(t + 2, bA)
    COMP(t + 1, bB)
  }
  PREF(31, bB)
  COMP(30, bA)
  COMP(31, bB)
#undef PREF
#undef COMP

  if (MODE == 0) {
#pragma unroll
    for (int m = 0; m < 4; ++m)
#pragma unroll
      for (int r = 0; r < 4; ++r)
        atomicAdd(&aggr[(size_t)s_dst[m * 16 + g * 4 + r] * CO + ocol], msg[m][r]);
  } else {
    float* Mb = (CI == 64 && (w >> 1)) ? m1 : m0;
#pragma unroll
    for (int m = 0; m < 4; ++m)
#pragma unroll
      for (int r = 0; r < 4; ++r)
        Mb[(size_t)(e0 + m * 16 + g * 4 + r) * CO + ocol] = msg[m][r];
  }
}

// ---- CSR aggregation: out[n,c] = R[n,c] + sum over incident edges of M ------
template <int CO, bool DUAL>
__global__ void k_aggr(const int* __restrict__ off, const int* __restrict__ order,
                       const float* __restrict__ M0, const float* __restrict__ M1,
                       const float* R, float* out) {
  const int tid = threadIdx.x;
  const int n = blockIdx.x * (256 / CO) + tid / CO;
  const int c = tid % CO;
  if (n >= NN) return;
  float acc = R[(size_t)n * CO + c];
  const int j0 = off[n], j1 = off[n + 1];
  for (int j = j0; j < j1; ++j) {
    const size_t e = (size_t)order[j];
    acc += M0[e * CO + c];
    if (DUAL) acc += M1[e * CO + c];
  }
  out[(size_t)n * CO + c] = acc;
}

extern "C" void kernel_launch(void* const* d_in, const int* in_sizes, int n_in,
                              void* d_out, int out_size, void* d_ws, size_t ws_size,
                              hipStream_t stream) {
  const float* x       = (const float*)d_in[0];
  const int*   ei      = (const int*)d_in[1];
  const float* eattr   = (const float*)d_in[2];
  const float* l1_ew1  = (const float*)d_in[3];
  const float* l1_eb1  = (const float*)d_in[4];
  const float* l1_ew2  = (const float*)d_in[5];
  const float* l1_eb2  = (const float*)d_in[6];
  const float* l1_root = (const float*)d_in[7];
  const float* l1_bias = (const float*)d_in[8];
  const float* l2_ew1  = (const float*)d_in[9];
  const float* l2_eb1  = (const float*)d_in[10];
  const float* l2_ew2  = (const float*)d_in[11];
  const float* l2_eb2  = (const float*)d_in[12];
  const float* l2_root = (const float*)d_in[13];
  const float* l2_bias = (const float*)d_in[14];

  const int* src = ei;
  const int* dst = ei + NE;

  // workspace layout (bytes)
  char* ws = (char*)d_ws;
  float* P1 = (float*)ws;                           // NN*64 f32 = 2,560,000 B
  float* R2 = (float*)(ws + 2560000);               // NN*32 f32 = 1,280,000 B
  unsigned short* B1  = (unsigned short*)(ws + 3840000);   // 524,288 B
  unsigned short* B2  = (unsigned short*)(ws + 4364288);   // 524,288 B
  unsigned short* B1e = (unsigned short*)(ws + 4888576);   // 8,192 B
  unsigned short* B2e = (unsigned short*)(ws + 4896768);   // 8,192 B
  int* cnt    = (int*)(ws + 4904960);               // 40,000 B
  int* off    = (int*)(ws + 4944960);               // 40,004 B
  int* cursor = (int*)(ws + 4984976);               // 40,000 B
  int* order  = (int*)(ws + 5024976);               // 160,000 B
  float* M    = (float*)(ws + 5185024);             // NE*64 f32 = 10,240,000 B
  const size_t WS_NEED = 5185024 + 10240000;
  float* outf = (float*)d_out;

  k_reorder<<<128, 256, 0, stream>>>(l1_ew2, B1);
  k_reorder<<<128, 256, 0, stream>>>(l2_ew2, B2);
  k_reorder_e<<<1, 512, 0, stream>>>(l1_ew1, B1e);
  k_reorder_e<<<1, 512, 0, stream>>>(l2_ew1, B2e);

  if (ws_size >= WS_NEED) {
    // ---- CSR path: no atomics in the hot kernels
    k_zero<<<(NN + 255) / 256, 256, 0, stream>>>(cnt, NN);
    k_hist<<<(NE + 255) / 256, 256, 0, stream>>>(dst, cnt);
    k_scan<<<1, 1024, 0, stream>>>(cnt, off);
    k_seed<<<(NN + 255) / 256, 256, 0, stream>>>(off, cursor);
    k_scatter<<<(NE + 255) / 256, 256, 0, stream>>>(dst, cursor, order);

    k_root<32, 64, false><<<(NN * 64 + 255) / 256, 256, 0, stream>>>(x, l1_root, l1_bias, P1);
    k_edge<32, 64, false, 1><<<NE / 64, 256, 0, stream>>>(
        src, dst, eattr, B1e, l1_eb1, B1, l1_eb2, x, nullptr, M, nullptr);
    k_aggr<64, false><<<(NN + 3) / 4, 256, 0, stream>>>(off, order, M, nullptr, P1, P1);

    k_root<64, 32, true><<<(NN * 32 + 255) / 256, 256, 0, stream>>>(P1, l2_root, l2_bias, R2);
    float* M2a = M;
    float* M2b = M + (size_t)NE * 32;
    k_edge<64, 32, true, 1><<<NE / 64, 256, 0, stream>>>(
        src, dst, eattr, B2e, l2_eb1, B2, l2_eb2, P1, nullptr, M2a, M2b);
    k_aggr<32, true><<<(NN + 7) / 8, 256, 0, stream>>>(off, order, M2a, M2b, R2, outf);
  } else {
    // ---- fallback: R3 atomic path
    k_root<32, 64, false><<<(NN * 64 + 255) / 256, 256, 0, stream>>>(x, l1_root, l1_bias, P1);
    k_edge<32, 64, false, 0><<<NE / 64, 256, 0, stream>>>(
        src, dst, eattr, B1e, l1_eb1, B1, l1_eb2, x, P1, nullptr, nullptr);
    k_root<64, 32, true><<<(NN * 32 + 255) / 256, 256, 0, stream>>>(P1, l2_root, l2_bias, outf);
    k_edge<64, 32, true, 0><<<NE / 64, 256, 0, stream>>>(
        src, dst, eattr, B2e, l2_eb1, B2, l2_eb2, P1, outf, nullptr, nullptr);
  }
}

// Round 14
// 120.862 us; speedup vs baseline: 1.1883x; 1.1883x over previous
//
#include <hip/hip_runtime.h>

#define NN 10000
#define NE 40000

typedef __attribute__((ext_vector_type(8))) short bf16x8;
typedef __attribute__((ext_vector_type(4))) float f32x4;
typedef __attribute__((ext_vector_type(8))) unsigned short u16x8;

__device__ inline unsigned short bf16rne(float f) {
  union { float f; unsigned u; } v; v.f = f;
  return (unsigned short)((v.u + 0x7FFFu + ((v.u >> 16) & 1u)) >> 16);
}

// ew2 [128 x 2048] f32 -> bf16 MFMA-B fragment order.
__global__ void k_reorder(const float* __restrict__ ew2, unsigned short* __restrict__ out) {
  const int l  = threadIdx.x & 63;
  const int kk = threadIdx.x >> 6;
  const int ct = blockIdx.x;
  const int col = ct * 16 + (l & 15);
  const int g = l >> 4;
  u16x8 v;
#pragma unroll
  for (int j = 0; j < 8; ++j) v[j] = bf16rne(ew2[(kk * 32 + g * 8 + j) * 2048 + col]);
  *reinterpret_cast<u16x8*>(out + ((size_t)(ct * 2048 + kk * 512 + l * 8))) = v;
}
__global__ void k_reorder_e(const float* __restrict__ ew1, unsigned short* __restrict__ out) {
  const int l  = threadIdx.x & 63;
  const int ct = threadIdx.x >> 6;
  const int g = l >> 4;
  u16x8 v;
#pragma unroll
  for (int j = 0; j < 8; ++j) {
    int k = g * 8 + j;
    v[j] = (k < 16) ? bf16rne(ew1[k * 128 + ct * 16 + (l & 15)]) : (unsigned short)0;
  }
  *reinterpret_cast<u16x8*>(out + ((size_t)(ct * 64 + l) * 8)) = v;
}

template <int KI, int KO, bool RELU_IN>
__global__ void k_root(const float* __restrict__ xin, const float* __restrict__ root,
                       const float* __restrict__ bias, float* __restrict__ out) {
  int idx = blockIdx.x * 256 + threadIdx.x;
  if (idx >= NN * KO) return;
  int n = idx / KO, o = idx % KO;
  float acc = bias[o];
#pragma unroll
  for (int k = 0; k < KI; ++k) {
    float v = xin[n * KI + k];
    if (RELU_IN) v = fmaxf(v, 0.f);
    acc += v * root[k * KO + o];
  }
  out[idx] = acc;
}

// Fused per-edge kernel (R3 structure) + per-block t-STAGGER: concurrent
// blocks walk the shared B-fragment stream at different phases, breaking
// the cross-block L2 same-line lockstep burst.
template <int CI, int CO, bool RELU_IN>
__global__ __launch_bounds__(256, 2) void k_edge(
    const int* __restrict__ src, const int* __restrict__ dst,
    const float* __restrict__ eattr,
    const unsigned short* __restrict__ ew1f, const float* __restrict__ eb1,
    const unsigned short* __restrict__ bfrag, const float* __restrict__ eb2,
    const float* __restrict__ xin, float* __restrict__ aggr) {
  constexpr int TE = 64;
  const int tid = threadIdx.x;
  const int e0 = blockIdx.x * TE;
  const int toff = blockIdx.x & 31;

  __shared__ int s_src[TE];
  __shared__ int s_dst[TE];
  __shared__ float s_x[CI][68];
  __shared__ unsigned short s_hfrag[16 * 64 * 8];  // 16 KB

  if (tid < TE) { s_src[tid] = src[e0 + tid]; s_dst[tid] = dst[e0 + tid]; }
  __syncthreads();

  for (int idx = tid; idx < TE * CI; idx += 256) {
    int e = idx / CI, c = idx % CI;
    float v = xin[(size_t)s_src[e] * CI + c];
    if (RELU_IN) v = fmaxf(v, 0.f);
    s_x[c][e] = v;
  }

  const int l = tid & 63, w = tid >> 6, g = l >> 4, c16 = l & 15;

  // H phase via MFMA: wave w -> edge tile m=w, all 128 channels
  {
    const int m = w;
    bf16x8 ea;
#pragma unroll
    for (int j = 0; j < 8; ++j) ea[j] = 0;
    if (g < 2) {
      const float* p = eattr + (size_t)(e0 + 16 * m + c16) * 16 + g * 8;
      f32x4 v0 = *reinterpret_cast<const f32x4*>(p);
      f32x4 v1 = *reinterpret_cast<const f32x4*>(p + 4);
#pragma unroll
      for (int j = 0; j < 4; ++j) { ea[j] = bf16rne(v0[j]); ea[4 + j] = bf16rne(v1[j]); }
    }
#pragma unroll
    for (int ct = 0; ct < 8; ++ct) {
      bf16x8 bw = *reinterpret_cast<const bf16x8*>(ew1f + (size_t)(ct * 64 + l) * 8);
      const float bb = eb1[ct * 16 + c16];
      f32x4 acc = {bb, bb, bb, bb};
      acc = __builtin_amdgcn_mfma_f32_16x16x32_bf16(ea, bw, acc, 0, 0, 0);
#pragma unroll
      for (int r = 0; r < 4; ++r) {
        const int c = ct * 16 + c16;
        s_hfrag[(((m * 4) + (c >> 5)) * 64 + ((c >> 3) & 3) * 16 + g * 4 + r) * 8 + (c & 7)] =
            bf16rne(fmaxf(acc[r], 0.f));
      }
    }
  }
  __syncthreads();

  bf16x8 afrag[4][4];
#pragma unroll
  for (int m = 0; m < 4; ++m)
#pragma unroll
    for (int kk = 0; kk < 4; ++kk)
      afrag[m][kk] = *reinterpret_cast<const bf16x8*>(&s_hfrag[((m * 4 + kk) * 64 + l) * 8]);

  float msg[4][4];
#pragma unroll
  for (int m = 0; m < 4; ++m)
#pragma unroll
    for (int r = 0; r < 4; ++r) msg[m][r] = 0.f;

  const int ocol = (CI == 32) ? (w * 16 + c16) : ((w & 1) * 16 + c16);
  const bf16x8* Bb = reinterpret_cast<const bf16x8*>(bfrag);

  bf16x8 bA[4], bB[4];

#define PREF(T, BUF)                                                             \
  {                                                                              \
    const int tt_ = ((T) + toff) & 31;                                           \
    const int i_ = (CI == 32) ? tt_ : ((w >> 1) + 2 * tt_);                      \
    const int ct_ = (CI == 32) ? (tt_ * 4 + w) : (i_ * 2 + (w & 1));             \
    const bf16x8* bp_ = Bb + (size_t)ct_ * 256 + l;                              \
    _Pragma("unroll") for (int kk = 0; kk < 4; ++kk) BUF[kk] = bp_[kk * 64];     \
  }

#define COMP(T, BUF)                                                             \
  {                                                                              \
    const int tt_ = ((T) + toff) & 31;                                           \
    const int i_ = (CI == 32) ? tt_ : ((w >> 1) + 2 * tt_);                      \
    const float bb = eb2[i_ * CO + ocol];                                        \
    _Pragma("unroll") for (int m = 0; m < 4; ++m) {                              \
      f32x4 wacc = {0.f, 0.f, 0.f, 0.f};                                         \
      _Pragma("unroll") for (int kk = 0; kk < 4; ++kk)                           \
          wacc = __builtin_amdgcn_mfma_f32_16x16x32_bf16(afrag[m][kk], BUF[kk],  \
                                                         wacc, 0, 0, 0);         \
      const f32x4 xs = *reinterpret_cast<const f32x4*>(&s_x[i_][m * 16 + g * 4]);\
      _Pragma("unroll") for (int r = 0; r < 4; ++r)                              \
          msg[m][r] += fmaxf(wacc[r] + bb, 0.f) * xs[r];                         \
    }                                                                            \
  }

  PREF(0, bA)
#pragma unroll 1
  for (int t = 0; t < 30; t += 2) {
    PREF(t + 1, bB)
    COMP(t, bA)
    PREF(t + 2, bA)
    COMP(t + 1, bB)
  }
  PREF(31, bB)
  COMP(30, bA)
  COMP(31, bB)
#undef PREF
#undef COMP

#pragma unroll
  for (int m = 0; m < 4; ++m)
#pragma unroll
    for (int r = 0; r < 4; ++r)
      atomicAdd(&aggr[(size_t)s_dst[m * 16 + g * 4 + r] * CO + ocol], msg[m][r]);
}

// ---- PROBE: exact t-loop + atomic epilogue, prologue stubbed ----------------
// afrag read from zeroed LDS (same ds pattern), s_x = 1.0, dst hashed.
// Measures whether the t-loop as-written is intrinsically the ~40us wall.
__global__ __launch_bounds__(256, 2) void p_tloop(
    const unsigned short* __restrict__ bfrag, const float* __restrict__ eb2,
    float* __restrict__ scr) {
  const int tid = threadIdx.x;
  const int e0 = blockIdx.x * 64;
  __shared__ float s_x[32][68];
  __shared__ unsigned short s_hfrag[16 * 64 * 8];
  for (int i = tid; i < 32 * 68; i += 256) (&s_x[0][0])[i] = 1.0f;
  for (int i = tid; i < 16 * 64 * 8; i += 256) s_hfrag[i] = 0;
  __syncthreads();
  const int l = tid & 63, w = tid >> 6, g = l >> 4, c16 = l & 15;
  bf16x8 afrag[4][4];
#pragma unroll
  for (int m = 0; m < 4; ++m)
#pragma unroll
    for (int kk = 0; kk < 4; ++kk)
      afrag[m][kk] = *reinterpret_cast<const bf16x8*>(&s_hfrag[((m * 4 + kk) * 64 + l) * 8]);
  float msg[4][4];
#pragma unroll
  for (int m = 0; m < 4; ++m)
#pragma unroll
    for (int r = 0; r < 4; ++r) msg[m][r] = 0.f;
  const int ocol = w * 16 + c16;
  const bf16x8* Bb = reinterpret_cast<const bf16x8*>(bfrag);
  bf16x8 bA[4], bB[4];
#define PPREF(T, BUF)                                                            \
  {                                                                              \
    const int ct_ = (T) * 4 + w;                                                 \
    const bf16x8* bp_ = Bb + (size_t)ct_ * 256 + l;                              \
    _Pragma("unroll") for (int kk = 0; kk < 4; ++kk) BUF[kk] = bp_[kk * 64];     \
  }
#define PCOMP(T, BUF)                                                            \
  {                                                                              \
    const float bb = eb2[(T) * 64 + ocol];                                       \
    _Pragma("unroll") for (int m = 0; m < 4; ++m) {                              \
      f32x4 wacc = {0.f, 0.f, 0.f, 0.f};                                         \
      _Pragma("unroll") for (int kk = 0; kk < 4; ++kk)                           \
          wacc = __builtin_amdgcn_mfma_f32_16x16x32_bf16(afrag[m][kk], BUF[kk],  \
                                                         wacc, 0, 0, 0);         \
      const f32x4 xs = *reinterpret_cast<const f32x4*>(&s_x[(T)][m * 16 + g * 4]);\
      _Pragma("unroll") for (int r = 0; r < 4; ++r)                              \
          msg[m][r] += fmaxf(wacc[r] + bb, 0.f) * xs[r];                         \
    }                                                                            \
  }
  PPREF(0, bA)
#pragma unroll 1
  for (int t = 0; t < 30; t += 2) {
    PPREF(t + 1, bB)
    PCOMP(t, bA)
    PPREF(t + 2, bA)
    PCOMP(t + 1, bB)
  }
  PPREF(31, bB)
  PCOMP(30, bA)
  PCOMP(31, bB)
#undef PPREF
#undef PCOMP
#pragma unroll
  for (int m = 0; m < 4; ++m)
#pragma unroll
    for (int r = 0; r < 4; ++r) {
      const unsigned e = (unsigned)(e0 + m * 16 + g * 4 + r) * 2654435761u % (unsigned)NN;
      atomicAdd(&scr[(size_t)e * 64 + ocol], msg[m][r]);
    }
}

extern "C" void kernel_launch(void* const* d_in, const int* in_sizes, int n_in,
                              void* d_out, int out_size, void* d_ws, size_t ws_size,
                              hipStream_t stream) {
  const float* x       = (const float*)d_in[0];
  const int*   ei      = (const int*)d_in[1];
  const float* eattr   = (const float*)d_in[2];
  const float* l1_ew1  = (const float*)d_in[3];
  const float* l1_eb1  = (const float*)d_in[4];
  const float* l1_ew2  = (const float*)d_in[5];
  const float* l1_eb2  = (const float*)d_in[6];
  const float* l1_root = (const float*)d_in[7];
  const float* l1_bias = (const float*)d_in[8];
  const float* l2_ew1  = (const float*)d_in[9];
  const float* l2_eb1  = (const float*)d_in[10];
  const float* l2_ew2  = (const float*)d_in[11];
  const float* l2_eb2  = (const float*)d_in[12];
  const float* l2_root = (const float*)d_in[13];
  const float* l2_bias = (const float*)d_in[14];

  const int* src = ei;
  const int* dst = ei + NE;

  char* ws = (char*)d_ws;
  float* P1 = (float*)ws;                                  // 2,560,000 B
  unsigned short* B1  = (unsigned short*)(ws + 2560000);   // 524,288 B
  unsigned short* B2  = (unsigned short*)(ws + 3084288);   // 524,288 B
  unsigned short* B1e = (unsigned short*)(ws + 3608576);   // 8,192 B
  unsigned short* B2e = (unsigned short*)(ws + 3616768);   // 8,192 B
  float* scr = (float*)(ws + 3624960);                     // 2,560,000 B probe scratch
  const size_t WS_NEED = 3624960 + 2560000;
  float* outf = (float*)d_out;

  k_reorder<<<128, 256, 0, stream>>>(l1_ew2, B1);
  k_reorder<<<128, 256, 0, stream>>>(l2_ew2, B2);
  k_reorder_e<<<1, 512, 0, stream>>>(l1_ew1, B1e);
  k_reorder_e<<<1, 512, 0, stream>>>(l2_ew1, B2e);

  k_root<32, 64, false><<<(NN * 64 + 255) / 256, 256, 0, stream>>>(x, l1_root, l1_bias, P1);
  k_edge<32, 64, false><<<NE / 64, 256, 0, stream>>>(src, dst, eattr, B1e, l1_eb1, B1, l1_eb2, x, P1);
  k_root<64, 32, true><<<(NN * 32 + 255) / 256, 256, 0, stream>>>(P1, l2_root, l2_bias, outf);
  k_edge<64, 32, true><<<NE / 64, 256, 0, stream>>>(src, dst, eattr, B2e, l2_eb1, B2, l2_eb2, P1, outf);

  if (ws_size >= WS_NEED)
    p_tloop<<<NE / 64, 256, 0, stream>>>(B1, l1_eb2, scr);
}

// Round 15
// 93.642 us; speedup vs baseline: 1.5337x; 1.2907x over previous
//
#include <hip/hip_runtime.h>

#define NN 10000
#define NE 40000

typedef __attribute__((ext_vector_type(8))) short bf16x8;
typedef __attribute__((ext_vector_type(4))) float f32x4;
typedef __attribute__((ext_vector_type(8))) unsigned short u16x8;

__device__ inline unsigned short bf16rne(float f) {
  union { float f; unsigned u; } v; v.f = f;
  return (unsigned short)((v.u + 0x7FFFu + ((v.u >> 16) & 1u)) >> 16);
}

// ew2 [128 x 2048] f32 -> bf16 MFMA-B fragment order under the sigma k-slot
// permutation: channel c <-> (kk=(c&15)>>2, g=(c&15)&3, j=c>>4).
// elem j of lane l (g=l>>4), chunk kk, col-tile ct = ew2[j*16+kk*4+g][ct*16+(l&15)]
// at ushort index ct*2048 + kk*512 + l*8 + j.
__global__ void k_reorder(const float* __restrict__ ew2, unsigned short* __restrict__ out) {
  const int l  = threadIdx.x & 63;
  const int kk = threadIdx.x >> 6;
  const int ct = blockIdx.x;
  const int col = ct * 16 + (l & 15);
  const int g = l >> 4;
  u16x8 v;
#pragma unroll
  for (int j = 0; j < 8; ++j) v[j] = bf16rne(ew2[(j * 16 + kk * 4 + g) * 2048 + col]);
  *reinterpret_cast<u16x8*>(out + ((size_t)(ct * 2048 + kk * 512 + l * 8))) = v;
}

// ew1 [16 x 128] f32 -> bf16 B-frag, K padded to 32 with zeros (identity slotting).
__global__ void k_reorder_e(const float* __restrict__ ew1, unsigned short* __restrict__ out) {
  const int l  = threadIdx.x & 63;
  const int ct = threadIdx.x >> 6;
  const int g = l >> 4;
  u16x8 v;
#pragma unroll
  for (int j = 0; j < 8; ++j) {
    int k = g * 8 + j;
    v[j] = (k < 16) ? bf16rne(ew1[k * 128 + ct * 16 + (l & 15)]) : (unsigned short)0;
  }
  *reinterpret_cast<u16x8*>(out + ((size_t)(ct * 64 + l) * 8)) = v;
}

template <int KI, int KO, bool RELU_IN>
__global__ void k_root(const float* __restrict__ xin, const float* __restrict__ root,
                       const float* __restrict__ bias, float* __restrict__ out) {
  int idx = blockIdx.x * 256 + threadIdx.x;
  if (idx >= NN * KO) return;
  int n = idx / KO, o = idx % KO;
  float acc = bias[o];
#pragma unroll
  for (int k = 0; k < KI; ++k) {
    float v = xin[n * KI + k];
    if (RELU_IN) v = fmaxf(v, 0.f);
    acc += v * root[k * KO + o];
  }
  out[idx] = acc;
}

// Fused per-edge kernel (R3 structure + t-stagger) with VECTORIZED prologue:
// - x-gather via f32x4 global loads (4x fewer VMEM ops)
// - H stores via u16x8 (4 stores/thread vs 32 scalars; sigma slotting makes
//   each thread own a full 8-reg lane row) -> bank conflicts ~eliminated.
template <int CI, int CO, bool RELU_IN>
__global__ __launch_bounds__(256, 2) void k_edge(
    const int* __restrict__ src, const int* __restrict__ dst,
    const float* __restrict__ eattr,
    const unsigned short* __restrict__ ew1f, const float* __restrict__ eb1,
    const unsigned short* __restrict__ bfrag, const float* __restrict__ eb2,
    const float* __restrict__ xin, float* __restrict__ aggr) {
  constexpr int TE = 64;
  const int tid = threadIdx.x;
  const int e0 = blockIdx.x * TE;
  const int toff = blockIdx.x & 31;

  __shared__ int s_src[TE];
  __shared__ int s_dst[TE];
  __shared__ float s_x[CI][68];
  __shared__ unsigned short s_hfrag[16 * 64 * 8];  // 16 KB

  if (tid < TE) { s_src[tid] = src[e0 + tid]; s_dst[tid] = dst[e0 + tid]; }
  __syncthreads();

  // gather x[src] -> transposed LDS, f32x4 global loads
  {
    constexpr int NQ = CI / 4;  // f32x4 chunks per row
    for (int idx = tid; idx < TE * NQ; idx += 256) {
      const int e = idx / NQ, q = idx % NQ;
      f32x4 v = *reinterpret_cast<const f32x4*>(&xin[(size_t)s_src[e] * CI + q * 4]);
#pragma unroll
      for (int u = 0; u < 4; ++u)
        s_x[q * 4 + u][e] = RELU_IN ? fmaxf(v[u], 0.f) : v[u];
    }
  }

  const int l = tid & 63, w = tid >> 6, g = l >> 4, c16 = l & 15;

  // ---- H phase via MFMA: wave w -> edge tile m=w; vectorized stores under sigma
  {
    const int m = w;
    bf16x8 ea;
#pragma unroll
    for (int j = 0; j < 8; ++j) ea[j] = 0;
    if (g < 2) {
      const float* p = eattr + (size_t)(e0 + 16 * m + c16) * 16 + g * 8;
      f32x4 v0 = *reinterpret_cast<const f32x4*>(p);
      f32x4 v1 = *reinterpret_cast<const f32x4*>(p + 4);
#pragma unroll
      for (int j = 0; j < 4; ++j) { ea[j] = bf16rne(v0[j]); ea[4 + j] = bf16rne(v1[j]); }
    }
    u16x8 hreg[4];
#pragma unroll
    for (int ct = 0; ct < 8; ++ct) {
      bf16x8 bw = *reinterpret_cast<const bf16x8*>(ew1f + (size_t)(ct * 64 + l) * 8);
      const float bb = eb1[ct * 16 + c16];
      f32x4 acc = {bb, bb, bb, bb};
      acc = __builtin_amdgcn_mfma_f32_16x16x32_bf16(ea, bw, acc, 0, 0, 0);
#pragma unroll
      for (int r = 0; r < 4; ++r) hreg[r][ct] = bf16rne(fmaxf(acc[r], 0.f));
    }
    const int kk_s = c16 >> 2, gg_s = c16 & 3;
#pragma unroll
    for (int r = 0; r < 4; ++r)
      *reinterpret_cast<u16x8*>(
          &s_hfrag[((m * 4 + kk_s) * 64 + gg_s * 16 + g * 4 + r) * 8]) = hreg[r];
  }
  __syncthreads();

  // A fragments reg-resident (linear conflict-free b128 reads; layout unchanged)
  bf16x8 afrag[4][4];
#pragma unroll
  for (int m = 0; m < 4; ++m)
#pragma unroll
    for (int kk = 0; kk < 4; ++kk)
      afrag[m][kk] = *reinterpret_cast<const bf16x8*>(&s_hfrag[((m * 4 + kk) * 64 + l) * 8]);

  float msg[4][4];
#pragma unroll
  for (int m = 0; m < 4; ++m)
#pragma unroll
    for (int r = 0; r < 4; ++r) msg[m][r] = 0.f;

  const int ocol = (CI == 32) ? (w * 16 + c16) : ((w & 1) * 16 + c16);
  const bf16x8* Bb = reinterpret_cast<const bf16x8*>(bfrag);

  bf16x8 bA[4], bB[4];

#define PREF(T, BUF)                                                             \
  {                                                                              \
    const int tt_ = ((T) + toff) & 31;                                           \
    const int i_ = (CI == 32) ? tt_ : ((w >> 1) + 2 * tt_);                      \
    const int ct_ = (CI == 32) ? (tt_ * 4 + w) : (i_ * 2 + (w & 1));             \
    const bf16x8* bp_ = Bb + (size_t)ct_ * 256 + l;                              \
    _Pragma("unroll") for (int kk = 0; kk < 4; ++kk) BUF[kk] = bp_[kk * 64];     \
  }

#define COMP(T, BUF)                                                             \
  {                                                                              \
    const int tt_ = ((T) + toff) & 31;                                           \
    const int i_ = (CI == 32) ? tt_ : ((w >> 1) + 2 * tt_);                      \
    const float bb = eb2[i_ * CO + ocol];                                        \
    _Pragma("unroll") for (int m = 0; m < 4; ++m) {                              \
      f32x4 wacc = {0.f, 0.f, 0.f, 0.f};                                         \
      _Pragma("unroll") for (int kk = 0; kk < 4; ++kk)                           \
          wacc = __builtin_amdgcn_mfma_f32_16x16x32_bf16(afrag[m][kk], BUF[kk],  \
                                                         wacc, 0, 0, 0);         \
      const f32x4 xs = *reinterpret_cast<const f32x4*>(&s_x[i_][m * 16 + g * 4]);\
      _Pragma("unroll") for (int r = 0; r < 4; ++r)                              \
          msg[m][r] += fmaxf(wacc[r] + bb, 0.f) * xs[r];                         \
    }                                                                            \
  }

  PREF(0, bA)
#pragma unroll 1
  for (int t = 0; t < 30; t += 2) {
    PREF(t + 1, bB)
    COMP(t, bA)
    PREF(t + 2, bA)
    COMP(t + 1, bB)
  }
  PREF(31, bB)
  COMP(30, bA)
  COMP(31, bB)
#undef PREF
#undef COMP

  // coalesced atomics: per instruction, 4 edges x 16 consecutive cols (64B runs)
#pragma unroll
  for (int m = 0; m < 4; ++m)
#pragma unroll
    for (int r = 0; r < 4; ++r)
      atomicAdd(&aggr[(size_t)s_dst[m * 16 + g * 4 + r] * CO + ocol], msg[m][r]);
}

extern "C" void kernel_launch(void* const* d_in, const int* in_sizes, int n_in,
                              void* d_out, int out_size, void* d_ws, size_t ws_size,
                              hipStream_t stream) {
  const float* x       = (const float*)d_in[0];
  const int*   ei      = (const int*)d_in[1];
  const float* eattr   = (const float*)d_in[2];
  const float* l1_ew1  = (const float*)d_in[3];
  const float* l1_eb1  = (const float*)d_in[4];
  const float* l1_ew2  = (const float*)d_in[5];
  const float* l1_eb2  = (const float*)d_in[6];
  const float* l1_root = (const float*)d_in[7];
  const float* l1_bias = (const float*)d_in[8];
  const float* l2_ew1  = (const float*)d_in[9];
  const float* l2_eb1  = (const float*)d_in[10];
  const float* l2_ew2  = (const float*)d_in[11];
  const float* l2_eb2  = (const float*)d_in[12];
  const float* l2_root = (const float*)d_in[13];
  const float* l2_bias = (const float*)d_in[14];

  const int* src = ei;
  const int* dst = ei + NE;

  char* ws = (char*)d_ws;
  float* P1 = (float*)ws;                                  // 2,560,000 B
  unsigned short* B1  = (unsigned short*)(ws + 2560000);   // 524,288 B
  unsigned short* B2  = (unsigned short*)(ws + 3084288);   // 524,288 B
  unsigned short* B1e = (unsigned short*)(ws + 3608576);   // 8,192 B
  unsigned short* B2e = (unsigned short*)(ws + 3616768);   // 8,192 B
  float* outf = (float*)d_out;

  k_reorder<<<128, 256, 0, stream>>>(l1_ew2, B1);
  k_reorder<<<128, 256, 0, stream>>>(l2_ew2, B2);
  k_reorder_e<<<1, 512, 0, stream>>>(l1_ew1, B1e);
  k_reorder_e<<<1, 512, 0, stream>>>(l2_ew1, B2e);

  k_root<32, 64, false><<<(NN * 64 + 255) / 256, 256, 0, stream>>>(x, l1_root, l1_bias, P1);
  k_edge<32, 64, false><<<NE / 64, 256, 0, stream>>>(src, dst, eattr, B1e, l1_eb1, B1, l1_eb2, x, P1);
  k_root<64, 32, true><<<(NN * 32 + 255) / 256, 256, 0, stream>>>(P1, l2_root, l2_bias, outf);
  k_edge<64, 32, true><<<NE / 64, 256, 0, stream>>>(src, dst, eattr, B2e, l2_eb1, B2, l2_eb2, P1, outf);
}